// Round 7
// baseline (752.571 us; speedup 1.0000x reference)
//
#include <hip/hip_runtime.h>
#include <hip/hip_bf16.h>

#define N_NODES 100000
#define F_IN    256
#define H_DIM   128
#define C_CLS   16
#define NB_SCAN ((N_NODES + 255) / 256)   // 391

typedef __attribute__((ext_vector_type(8))) short  short8;
typedef __attribute__((ext_vector_type(4))) float  float4v;
typedef __attribute__((ext_vector_type(4))) unsigned short ushort4v;

__device__ __forceinline__ float b2f(ushort u) {
    union { unsigned int i; float f; } v;
    v.i = ((unsigned int)u) << 16;
    return v.f;
}

__device__ __forceinline__ ushort f2b(float f) {
    unsigned int x = __float_as_uint(f);
    unsigned int r = (x + 0x7FFFu + ((x >> 16) & 1u)) >> 16;   // RNE
    return (ushort)r;
}

__device__ __forceinline__ float ldsel(const void* p, int i, int f32f) {
    return f32f ? ((const float*)p)[i] : b2f(((const ushort*)p)[i]);
}

// ------------------------------------------------------------------ sniff ---
__global__ __launch_bounds__(64) void sniff(const ushort* __restrict__ x,
                                            const int* __restrict__ ei,
                                            int* __restrict__ flags) {
    int lane = threadIdx.x;
    int cnt_bf = 0;
#pragma unroll
    for (int j = 0; j < 4; ++j) {
        ushort u = x[lane * 4 + j];
        int e = (u >> 7) & 0xFF;
        if ((e >= 100 && e <= 140) || (u & 0x7FFF) == 0) cnt_bf++;
    }
    int zodd = (ei[2 * lane + 1] == 0) ? 1 : 0;
#pragma unroll
    for (int off = 32; off >= 1; off >>= 1) {
        cnt_bf += __shfl_xor(cnt_bf, off, 64);
        zodd   += __shfl_xor(zodd,   off, 64);
    }
    if (lane == 0) {
        flags[0] = (cnt_bf < 230) ? 1 : 0;   // f32 inputs
        flags[1] = (zodd  >= 32) ? 1 : 0;    // int64 indices
    }
}

// ---------------------- prep: ei -> int32 src/dst arrays + degree count -----
__global__ __launch_bounds__(256) void prep(const int* __restrict__ flags,
                                            const int* __restrict__ ei,
                                            int* __restrict__ src32,
                                            int* __restrict__ dst32,
                                            int* __restrict__ cnt, int E) {
    int e = blockIdx.x * 256 + threadIdx.x;
    if (e >= E) return;
    int i64 = flags[1];
    int s = i64 ? ei[2L * e]          : ei[e];
    int d = i64 ? ei[2L * E + 2L * e] : ei[(long)E + e];
    src32[e] = s;
    dst32[e] = d;
    atomicAdd(&cnt[d], 1);
}

// ------------------------------------------------------------ 3-step scan ---
__global__ __launch_bounds__(256) void scan1(const int* __restrict__ cnt,
                                             int* __restrict__ offs,
                                             int* __restrict__ bsum) {
    __shared__ int sd[256];
    int t = threadIdx.x;
    int i = blockIdx.x * 256 + t;
    int v = (i < N_NODES) ? cnt[i] : 0;
    sd[t] = v;
    __syncthreads();
#pragma unroll
    for (int d = 1; d < 256; d <<= 1) {
        int add = (t >= d) ? sd[t - d] : 0;
        __syncthreads();
        sd[t] += add;
        __syncthreads();
    }
    if (i < N_NODES) offs[i] = sd[t] - v;          // exclusive within block
    if (t == 255) bsum[blockIdx.x] = sd[255];
}

__global__ __launch_bounds__(512) void scan2(const int* __restrict__ bsum,
                                             int* __restrict__ boff) {
    __shared__ int sd[512];
    int t = threadIdx.x;
    int v = (t < NB_SCAN) ? bsum[t] : 0;
    sd[t] = v;
    __syncthreads();
#pragma unroll
    for (int d = 1; d < 512; d <<= 1) {
        int add = (t >= d) ? sd[t - d] : 0;
        __syncthreads();
        sd[t] += add;
        __syncthreads();
    }
    if (t < NB_SCAN) boff[t] = sd[t] - v;          // exclusive
}

// offs -> global offsets; also cursor copy and dis = rsqrt(deg) fused
__global__ __launch_bounds__(256) void scan3(int* __restrict__ offs,
                                             const int* __restrict__ boff,
                                             const int* __restrict__ cnt,
                                             int* __restrict__ cursor,
                                             float* __restrict__ dis, int E) {
    int i = blockIdx.x * 256 + threadIdx.x;
    if (i == 0) offs[N_NODES] = E;
    if (i >= N_NODES) return;
    int off = offs[i] + boff[i >> 8];
    offs[i] = off;
    cursor[i] = off;
    dis[i] = rsqrtf((float)(cnt[i] + 1));          // +1 self-loop
}

// ------------------------------------------------------ permutation build ---
// perm2[slot] = (src, dis[src]) so the gather loop has no dependent dis read
__global__ __launch_bounds__(256) void build_perm(const int* __restrict__ src32,
                                                  const int* __restrict__ dst32,
                                                  const float* __restrict__ dis,
                                                  int* __restrict__ cursor,
                                                  int2* __restrict__ perm2, int E) {
    int e = blockIdx.x * 256 + threadIdx.x;
    if (e >= E) return;
    int s = src32[e];
    int d = dst32[e];
    int slot = atomicAdd(&cursor[d], 1);
    perm2[slot] = make_int2(s, __float_as_int(dis[s]));
}

// -------------------------------------------------------------- h = x @ W ---
// Dual-dtype: reads x/W directly as bf16 or f32 (wave-uniform branch),
// converting to bf16 fragments in registers. No separate convert pass.
__global__ __launch_bounds__(256) void gemm_xw(const int* __restrict__ flags,
                                               const ushort* __restrict__ x_b,
                                               const float* __restrict__ x_f,
                                               const ushort* __restrict__ W_b,
                                               const float* __restrict__ W_f,
                                               ushort* __restrict__ hout) {
    __shared__ __align__(16) ushort wt[128][128 + 8];   // 34816 B
    const int f32f = flags[0];

    const int tid  = threadIdx.x;
    const int lane = tid & 63;
    const int wave = tid >> 6;
    const int quad = lane >> 4;
    const int lm   = lane & 15;

    const int rbase = blockIdx.x * 64 + wave * 16;
    int arow = rbase + lm;
    if (arow >= N_NODES) arow = N_NODES - 1;      // clamp; store is guarded

    float4v acc[8];
#pragma unroll
    for (int c = 0; c < 8; ++c) acc[c] = (float4v){0.f, 0.f, 0.f, 0.f};

    for (int hh = 0; hh < 2; ++hh) {
        if (hh) __syncthreads();
#pragma unroll
        for (int it = 0; it < 8; ++it) {
            int flat = (it * 256 + tid) * 8;       // 0..16384
            int kl = flat >> 7;
            int c0 = flat & 127;
            if (!f32f) {
                short8 v = *(const short8*)(W_b + hh * 16384 + flat);
#pragma unroll
                for (int j = 0; j < 8; ++j) wt[c0 + j][kl] = (ushort)v[j];
            } else {
                float4 a = *(const float4*)(W_f + hh * 16384 + flat);
                float4 b = *(const float4*)(W_f + hh * 16384 + flat + 4);
                wt[c0 + 0][kl] = f2b(a.x); wt[c0 + 1][kl] = f2b(a.y);
                wt[c0 + 2][kl] = f2b(a.z); wt[c0 + 3][kl] = f2b(a.w);
                wt[c0 + 4][kl] = f2b(b.x); wt[c0 + 5][kl] = f2b(b.y);
                wt[c0 + 6][kl] = f2b(b.z); wt[c0 + 7][kl] = f2b(b.w);
            }
        }
        __syncthreads();
#pragma unroll
        for (int s = 0; s < 4; ++s) {
            int klocal = s * 32 + quad * 8;
            short8 afrag;
            if (!f32f) {
                afrag = *(const short8*)(x_b + (size_t)arow * F_IN + hh * 128 + klocal);
            } else {
                const float* xr = x_f + (size_t)arow * F_IN + hh * 128 + klocal;
                float4 a = *(const float4*)xr;
                float4 b = *(const float4*)(xr + 4);
                afrag[0] = (short)f2b(a.x); afrag[1] = (short)f2b(a.y);
                afrag[2] = (short)f2b(a.z); afrag[3] = (short)f2b(a.w);
                afrag[4] = (short)f2b(b.x); afrag[5] = (short)f2b(b.y);
                afrag[6] = (short)f2b(b.z); afrag[7] = (short)f2b(b.w);
            }
#pragma unroll
            for (int c = 0; c < 8; ++c) {
                short8 bfrag = *(const short8*)(&wt[c * 16 + lm][klocal]);
                acc[c] = __builtin_amdgcn_mfma_f32_16x16x32_bf16(afrag, bfrag, acc[c], 0, 0, 0);
            }
        }
    }
    // D[row=quad*4+r][col=lane&15]
#pragma unroll
    for (int c = 0; c < 8; ++c) {
        int col = c * 16 + lm;
#pragma unroll
        for (int r = 0; r < 4; ++r) {
            int node = rbase + quad * 4 + r;
            if (node < N_NODES) hout[(size_t)node * H_DIM + col] = f2b(acc[c][r]);
        }
    }
}

// ------------------- fused gather-reduce + bias/relu + bayes linear + lsm ---
// TWO waves per node (each takes half the CSR segment) -> 200k waves, ~8
// gathers each: halves the per-wave serial chain that R6 showed to be the
// wall. Partials combined via 1KB LDS + one __syncthreads; epilogue on the
// even wave only. Inner loop identical to R6 (perm2-packed (s,w), shfl
// broadcast, uniform 16-batches with zero-weight masking).
__global__ __launch_bounds__(256) void gather_final(const int* __restrict__ flags,
                                                    const int* __restrict__ offs,
                                                    const int2* __restrict__ perm2,
                                                    const float* __restrict__ dis,
                                                    const ushort* __restrict__ hb,
                                                    const void* __restrict__ gcn_b,
                                                    const void* __restrict__ w_mu,
                                                    const void* __restrict__ w_ls,
                                                    const void* __restrict__ b_mu,
                                                    const void* __restrict__ b_ls,
                                                    const void* __restrict__ eps_w,
                                                    const void* __restrict__ eps_b,
                                                    void* __restrict__ out) {
    __shared__ float2 comb[2][64];
    const int f32f = flags[0];
    const int lane = threadIdx.x & 63;
    const int wv   = threadIdx.x >> 6;
    const int nl   = wv >> 1;          // local node 0..1
    const int hf   = wv & 1;           // which half of the edge list
    const int node = blockIdx.x * 2 + nl;   // N even -> always valid

    const int o0  = offs[node];
    const int deg = offs[node + 1] - o0;
    const int halfc   = (deg + 1) >> 1;
    const int mystart = o0 + (hf ? halfc : 0);
    const int mycount = hf ? (deg - halfc) : halfc;

    float ax = 0.f, ay = 0.f;
    for (int base = 0; base < mycount; base += 64) {
        int rem = mycount - base;
        if (rem > 64) rem = 64;
        int s_l = 0; float w_l = 0.f;
        if (lane < rem) {
            int2 pr = perm2[mystart + base + lane];
            s_l = pr.x;
            w_l = __int_as_float(pr.y);
        }
        // uniform batches of 16; slots >= rem have s=0,w=0 (harmless row-0 hit)
        for (int jj = 0; jj < rem; jj += 16) {
            int   sv[16];
            float wv16[16];
#pragma unroll
            for (int k = 0; k < 16; ++k) {
                sv[k]   = __shfl(s_l, jj + k, 64);
                wv16[k] = __shfl(w_l, jj + k, 64);
            }
            uint u[16];
#pragma unroll
            for (int k = 0; k < 16; ++k)
                u[k] = *((const uint*)(hb + (size_t)sv[k] * H_DIM) + lane);
#pragma unroll
            for (int k = 0; k < 16; ++k) {
                float lo = __uint_as_float(u[k] << 16);
                float hi = __uint_as_float(u[k] & 0xFFFF0000u);
                ax = fmaf(wv16[k], lo, ax);
                ay = fmaf(wv16[k], hi, ay);
            }
        }
    }

    if (hf) comb[nl][lane] = make_float2(ax, ay);
    __syncthreads();
    if (hf) return;
    float2 ot = comb[nl][lane];
    ax += ot.x; ay += ot.y;

    // self-loop + bias + relu
    float dd = dis[node];
    uint us = *((const uint*)(hb + (size_t)node * H_DIM) + lane);
    float slo = __uint_as_float(us << 16);
    float shi = __uint_as_float(us & 0xFFFF0000u);
    ax = ax * dd + slo * dd * dd + ldsel(gcn_b, 2 * lane, f32f);
    ay = ay * dd + shi * dd * dd + ldsel(gcn_b, 2 * lane + 1, f32f);
    ax = fmaxf(ax, 0.f);
    ay = fmaxf(ay, 0.f);

    float p[C_CLS];
#pragma unroll
    for (int c = 0; c < C_CLS; ++c) {
        int i0 = c * H_DIM + 2 * lane;
        float wx = ldsel(w_mu, i0, f32f)     + __expf(ldsel(w_ls, i0, f32f))     * ldsel(eps_w, i0, f32f);
        float wy = ldsel(w_mu, i0 + 1, f32f) + __expf(ldsel(w_ls, i0 + 1, f32f)) * ldsel(eps_w, i0 + 1, f32f);
        p[c] = ax * wx + ay * wy;
    }
#pragma unroll
    for (int off = 32; off >= 1; off >>= 1) {
#pragma unroll
        for (int c = 0; c < C_CLS; ++c) p[c] += __shfl_xor(p[c], off, 64);
    }
#pragma unroll
    for (int c = 0; c < C_CLS; ++c)
        p[c] += ldsel(b_mu, c, f32f) + __expf(ldsel(b_ls, c, f32f)) * ldsel(eps_b, c, f32f);

    float m = p[0];
#pragma unroll
    for (int c = 1; c < C_CLS; ++c) m = fmaxf(m, p[c]);
    float ssum = 0.f;
#pragma unroll
    for (int c = 0; c < C_CLS; ++c) ssum += __expf(p[c] - m);
    float lse = m + __logf(ssum);

    if (lane == 0) {
        if (f32f) {
            float* op = (float*)out + (size_t)node * C_CLS;
            float4 o[4];
#pragma unroll
            for (int c = 0; c < C_CLS; ++c) ((float*)o)[c] = p[c] - lse;
#pragma unroll
            for (int q = 0; q < 4; ++q) ((float4*)op)[q] = o[q];
        } else {
            ushort* op = (ushort*)out + (size_t)node * C_CLS;
            ushort4v o[4];
#pragma unroll
            for (int c = 0; c < C_CLS; ++c) ((ushort*)o)[c] = f2b(p[c] - lse);
#pragma unroll
            for (int q = 0; q < 4; ++q) ((ushort4v*)op)[q] = o[q];
        }
    }
}

// ---------------------------------------------------------------------------
extern "C" void kernel_launch(void* const* d_in, const int* in_sizes, int n_in,
                              void* d_out, int out_size, void* d_ws, size_t ws_size,
                              hipStream_t stream) {
    const int E = in_sizes[1] / 2;

    char* wp = (char*)d_ws;
    auto alloc = [&](size_t bytes) -> char* {
        char* p = wp; wp += (bytes + 511) & ~(size_t)511; return p;
    };
    int*    flags  = (int*)   alloc(64);
    ushort* hb     = (ushort*)alloc((size_t)N_NODES * H_DIM * 2);   // bf16 h
    int*    cnt    = (int*)   alloc((size_t)N_NODES * 4);
    int*    offs   = (int*)   alloc((size_t)(N_NODES + 1) * 4);
    int*    cursor = (int*)   alloc((size_t)N_NODES * 4);
    int*    bsum   = (int*)   alloc((size_t)NB_SCAN * 4);
    int*    boff   = (int*)   alloc((size_t)NB_SCAN * 4);
    float*  dis    = (float*) alloc((size_t)N_NODES * 4);
    int2*   perm2  = (int2*)  alloc((size_t)E * 8);
    int*    src32  = (int*)   alloc((size_t)E * 4);
    int*    dst32  = (int*)   alloc((size_t)E * 4);

    sniff<<<1, 64, 0, stream>>>((const ushort*)d_in[0], (const int*)d_in[1], flags);
    (void)hipMemsetAsync(cnt, 0, (size_t)N_NODES * 4, stream);
    prep<<<(E + 255) / 256, 256, 0, stream>>>(flags, (const int*)d_in[1], src32, dst32, cnt, E);
    scan1<<<NB_SCAN, 256, 0, stream>>>(cnt, offs, bsum);
    scan2<<<1, 512, 0, stream>>>(bsum, boff);
    scan3<<<NB_SCAN, 256, 0, stream>>>(offs, boff, cnt, cursor, dis, E);
    build_perm<<<(E + 255) / 256, 256, 0, stream>>>(src32, dst32, dis, cursor, perm2, E);
    gemm_xw<<<(N_NODES + 63) / 64, 256, 0, stream>>>(flags,
                 (const ushort*)d_in[0], (const float*)d_in[0],
                 (const ushort*)d_in[2], (const float*)d_in[2], hb);
    gather_final<<<N_NODES / 2, 256, 0, stream>>>(flags, offs, perm2, dis, hb,
                 d_in[3], d_in[4], d_in[5], d_in[6], d_in[7], d_in[8], d_in[9], (void*)d_out);
}